// Round 1
// baseline (307.252 us; speedup 1.0000x reference)
//
#include <hip/hip_runtime.h>
#include <cstdint>
#include <cstddef>

#define BB 32
#define TT 14
#define DD 1024
#define RR 4
#define VV 8192
#define NCOL (VV*RR*RR)   // 131072

// ws layout (floats):
//  xT    : D*B   = 32768  @ 0        (x transposed: xT[d*32+b], for GEMM broadcast)
//  xb    : B*D   = 32768  @ 32768    (x b-major, for alpha/beta kernel)
//  cm    : B*16  = 512    @ 65536
//  sel   : B*T*16= 7168   @ 66048
//  alpha : B*4   = 128    @ 73216
//  beta  : B*4   = 128    @ 73344

__global__ __launch_bounds__(256) void k_prep(const float* __restrict__ in,
                                              float* __restrict__ xT,
                                              float* __restrict__ xb) {
    int tid = blockIdx.x * 256 + threadIdx.x;   // 32768 threads
    int b = tid >> 10, d = tid & 1023;
    float s = 0.f;
    #pragma unroll
    for (int t = 0; t < TT; ++t) s += in[(b * TT + t) * DD + d];
    s *= (1.0f / TT);
    xT[d * BB + b] = s;
    xb[b * DD + d] = s;
}

__global__ __launch_bounds__(256) void k_ab(const float* __restrict__ xb,
                                            const float* __restrict__ wa,
                                            const float* __restrict__ wb,
                                            float* __restrict__ alpha,
                                            float* __restrict__ beta) {
    int wid  = (blockIdx.x * 256 + threadIdx.x) >> 6;  // 0..255 waves
    int lane = threadIdx.x & 63;
    int b = wid >> 3, r = (wid >> 1) & 3, s = wid & 1;
    const float* wm = s ? wb : wa;
    float p = 0.f;
    #pragma unroll
    for (int k = 0; k < 16; ++k) {
        int d = lane + 64 * k;
        p += xb[b * DD + d] * wm[d * RR + r];
    }
    #pragma unroll
    for (int m = 1; m < 64; m <<= 1) p += __shfl_xor(p, m);
    if (lane == 0) {
        float v = 1.0f / (1.0f + __expf(-p)) + 0.001f;
        (s ? beta : alpha)[b * RR + r] = v;
    }
}

__global__ __launch_bounds__(256) void k_core(const float* __restrict__ wv,
                                              const float* __restrict__ xT,
                                              const int*   __restrict__ lab,
                                              float* __restrict__ cm,
                                              float* __restrict__ sel) {
    const int n    = blockIdx.x * 256 + threadIdx.x;   // column 0..131071
    const int lane = threadIdx.x & 63;
    const float4* __restrict__ x4 = reinterpret_cast<const float4*>(xT);

    float acc[BB];
    #pragma unroll
    for (int b = 0; b < BB; ++b) acc[b] = 0.f;

    #pragma unroll 1
    for (int d0 = 0; d0 < DD; d0 += 16) {
        float w[16];
        #pragma unroll
        for (int u = 0; u < 16; ++u)
            w[u] = __builtin_nontemporal_load(&wv[(size_t)(d0 + u) * NCOL + n]);
        #pragma unroll
        for (int u = 0; u < 16; ++u) {
            #pragma unroll
            for (int g = 0; g < 8; ++g) {         // 8 float4 = 32 b's, uniform -> s_load
                float4 xa = x4[(d0 + u) * 8 + g];
                acc[4*g+0] = fmaf(xa.x, w[u], acc[4*g+0]);
                acc[4*g+1] = fmaf(xa.y, w[u], acc[4*g+1]);
                acc[4*g+2] = fmaf(xa.z, w[u], acc[4*g+2]);
                acc[4*g+3] = fmaf(xa.w, w[u], acc[4*g+3]);
            }
        }
    }

    float c[BB];
    #pragma unroll
    for (int b = 0; b < BB; ++b)
        c[b] = 0.01f / (1.0f + __expf(-acc[b])) + 0.001f;

    const int i = n >> 15;            // which r1 block (0..3)
    const int v = (n >> 2) & (VV-1);  // vocab index
    const int j = n & 3;              // r2

    // cm[b][i][j] += sum over this wave's 16 v's (per j)
    #pragma unroll
    for (int b = 0; b < BB; ++b) {
        float s = c[b];
        s += __shfl_xor(s, 4);
        s += __shfl_xor(s, 8);
        s += __shfl_xor(s, 16);
        s += __shfl_xor(s, 32);
        if (lane < 4) atomicAdd(&cm[b * 16 + (i << 2) + lane], s);
    }

    // sel[b][t][i][j] = core[b, i, lab[b,t], j]
    #pragma unroll
    for (int b = 0; b < BB; ++b) {
        float cb = c[b];
        for (int t = 0; t < TT; ++t) {
            if (lab[b * TT + t] == v)
                sel[(b * TT + t) * 16 + (i << 2) + j] = cb;
        }
    }
}

__global__ __launch_bounds__(64) void k_final(const float* __restrict__ cm,
                                              const float* __restrict__ sel,
                                              const float* __restrict__ alpha,
                                              const float* __restrict__ beta,
                                              float* __restrict__ out) {
    __shared__ float ls[BB];
    int b = threadIdx.x;
    if (b < BB) {
        float ch[16], tmp[16];
        #pragma unroll
        for (int q = 0; q < 16; ++q) ch[q] = sel[(b * TT + 0) * 16 + q];
        for (int t = 1; t < TT; ++t) {
            const float* m = &sel[(b * TT + t) * 16];
            #pragma unroll
            for (int i2 = 0; i2 < 4; ++i2)
                #pragma unroll
                for (int j2 = 0; j2 < 4; ++j2) {
                    float s = 0.f;
                    #pragma unroll
                    for (int k = 0; k < 4; ++k) s += ch[i2*4+k] * m[k*4+j2];
                    tmp[i2*4+j2] = s;
                }
            #pragma unroll
            for (int q = 0; q < 16; ++q) ch[q] = tmp[q];
        }

        float M[16], P[16];
        #pragma unroll
        for (int q = 0; q < 16; ++q) { M[q] = cm[b*16+q]; P[q] = M[q]; }
        for (int t = 0; t < TT; ++t) {   // P = cm^(T+1)
            #pragma unroll
            for (int i2 = 0; i2 < 4; ++i2)
                #pragma unroll
                for (int j2 = 0; j2 < 4; ++j2) {
                    float s = 0.f;
                    #pragma unroll
                    for (int k = 0; k < 4; ++k) s += P[i2*4+k] * M[k*4+j2];
                    tmp[i2*4+j2] = s;
                }
            #pragma unroll
            for (int q = 0; q < 16; ++q) P[q] = tmp[q];
        }

        float a[4], be[4];
        #pragma unroll
        for (int r = 0; r < 4; ++r) { a[r] = alpha[b*4+r]; be[r] = beta[b*4+r]; }
        float un = 0.f, no = 0.f;
        #pragma unroll
        for (int i2 = 0; i2 < 4; ++i2)
            #pragma unroll
            for (int j2 = 0; j2 < 4; ++j2) {
                un += a[i2] * ch[i2*4+j2] * be[j2];
                no += a[i2] * P [i2*4+j2] * be[j2];
            }
        float prob = un / no + 0.001f;
        ls[b] = -logf(prob);
    }
    __syncthreads();
    if (threadIdx.x == 0) {
        float s = 0.f;
        for (int q = 0; q < BB; ++q) s += ls[q];
        out[0] = s / BB;
    }
}

extern "C" void kernel_launch(void* const* d_in, const int* in_sizes, int n_in,
                              void* d_out, int out_size, void* d_ws, size_t ws_size,
                              hipStream_t stream) {
    const float* in_embs = (const float*)d_in[0];
    const int*   lab     = (const int*)  d_in[1];
    const float* wa      = (const float*)d_in[2];
    const float* wb      = (const float*)d_in[3];
    const float* wv      = (const float*)d_in[4];

    float* ws    = (float*)d_ws;
    float* xT    = ws;
    float* xb    = ws + 32768;
    float* cm    = ws + 65536;
    float* sel   = ws + 66048;
    float* alpha = ws + 73216;
    float* beta  = ws + 73344;

    hipMemsetAsync(cm, 0, 512 * sizeof(float), stream);
    k_prep <<<128, 256, 0, stream>>>(in_embs, xT, xb);
    k_ab   <<<64,  256, 0, stream>>>(xb, wa, wb, alpha, beta);
    k_core <<<512, 256, 0, stream>>>(wv, xT, lab, cm, sel);
    k_final<<<1,   64,  0, stream>>>(cm, sel, alpha, beta, (float*)d_out);
}

// Round 2
// 257.294 us; speedup vs baseline: 1.1942x; 1.1942x over previous
//
#include <hip/hip_runtime.h>
#include <cstdint>
#include <cstddef>

#define BB 32
#define TT 14
#define DD 1024
#define RR 4
#define VV 8192
#define NCOL (VV*RR*RR)   // 131072 columns
#define WROW (NCOL/4)     // 32768 float4 per row

// ws layout (floats):
//  xT    : D*B   = 32768  @ 0        (xT[d*32+b])
//  xb    : B*D   = 32768  @ 32768    (b-major)
//  cm    : B*16  = 512    @ 65536
//  sel   : B*T*16= 7168   @ 66048
//  alpha : B*4   = 128    @ 73216
//  beta  : B*4   = 128    @ 73344

__global__ __launch_bounds__(256) void k_prep(const float* __restrict__ in,
                                              float* __restrict__ xT,
                                              float* __restrict__ xb,
                                              float* __restrict__ cm) {
    int tid = blockIdx.x * 256 + threadIdx.x;   // 32768 threads
    int b = tid >> 10, d = tid & 1023;
    float s = 0.f;
    #pragma unroll
    for (int t = 0; t < TT; ++t) s += in[(b * TT + t) * DD + d];
    s *= (1.0f / TT);
    xT[d * BB + b] = s;
    xb[b * DD + d] = s;
    if (tid < BB * 16) cm[tid] = 0.f;           // replaces hipMemsetAsync
}

__global__ __launch_bounds__(256) void k_ab(const float* __restrict__ xb,
                                            const float* __restrict__ wa,
                                            const float* __restrict__ wb,
                                            float* __restrict__ alpha,
                                            float* __restrict__ beta) {
    int wid  = (blockIdx.x * 256 + threadIdx.x) >> 6;
    int lane = threadIdx.x & 63;
    int b = wid >> 3, r = (wid >> 1) & 3, s = wid & 1;
    const float* wm = s ? wb : wa;
    float p = 0.f;
    #pragma unroll
    for (int k = 0; k < 16; ++k) {
        int d = lane + 64 * k;
        p += xb[b * DD + d] * wm[d * RR + r];
    }
    #pragma unroll
    for (int m = 1; m < 64; m <<= 1) p += __shfl_xor(p, m);
    if (lane == 0) {
        float v = 1.0f / (1.0f + __expf(-p)) + 0.001f;
        (s ? beta : alpha)[b * RR + r] = v;
    }
}

#define FMA_ROW(W, X0, X1)                                             \
    do {                                                               \
        acc[0].x = fmaf((W).x, (X0).x, acc[0].x);                      \
        acc[0].y = fmaf((W).y, (X0).x, acc[0].y);                      \
        acc[0].z = fmaf((W).z, (X0).x, acc[0].z);                      \
        acc[0].w = fmaf((W).w, (X0).x, acc[0].w);                      \
        acc[1].x = fmaf((W).x, (X0).y, acc[1].x);                      \
        acc[1].y = fmaf((W).y, (X0).y, acc[1].y);                      \
        acc[1].z = fmaf((W).z, (X0).y, acc[1].z);                      \
        acc[1].w = fmaf((W).w, (X0).y, acc[1].w);                      \
        acc[2].x = fmaf((W).x, (X0).z, acc[2].x);                      \
        acc[2].y = fmaf((W).y, (X0).z, acc[2].y);                      \
        acc[2].z = fmaf((W).z, (X0).z, acc[2].z);                      \
        acc[2].w = fmaf((W).w, (X0).z, acc[2].w);                      \
        acc[3].x = fmaf((W).x, (X0).w, acc[3].x);                      \
        acc[3].y = fmaf((W).y, (X0).w, acc[3].y);                      \
        acc[3].z = fmaf((W).z, (X0).w, acc[3].z);                      \
        acc[3].w = fmaf((W).w, (X0).w, acc[3].w);                      \
        acc[4].x = fmaf((W).x, (X1).x, acc[4].x);                      \
        acc[4].y = fmaf((W).y, (X1).x, acc[4].y);                      \
        acc[4].z = fmaf((W).z, (X1).x, acc[4].z);                      \
        acc[4].w = fmaf((W).w, (X1).x, acc[4].w);                      \
        acc[5].x = fmaf((W).x, (X1).y, acc[5].x);                      \
        acc[5].y = fmaf((W).y, (X1).y, acc[5].y);                      \
        acc[5].z = fmaf((W).z, (X1).y, acc[5].z);                      \
        acc[5].w = fmaf((W).w, (X1).y, acc[5].w);                      \
        acc[6].x = fmaf((W).x, (X1).z, acc[6].x);                      \
        acc[6].y = fmaf((W).y, (X1).z, acc[6].y);                      \
        acc[6].z = fmaf((W).z, (X1).z, acc[6].z);                      \
        acc[6].w = fmaf((W).w, (X1).z, acc[6].w);                      \
        acc[7].x = fmaf((W).x, (X1).w, acc[7].x);                      \
        acc[7].y = fmaf((W).y, (X1).w, acc[7].y);                      \
        acc[7].z = fmaf((W).z, (X1).w, acc[7].z);                      \
        acc[7].w = fmaf((W).w, (X1).w, acc[7].w);                      \
    } while (0)

// Each lane: 4 consecutive columns (float4 of wv) x 8 b's, all 1024 rows.
// 4 waves of a block = the 4 b-quarters, sharing the same 1KB w row-segment (L1).
__global__ __launch_bounds__(256) void k_core(const float* __restrict__ wv,
                                              const float* __restrict__ xT,
                                              const int*   __restrict__ lab,
                                              float* __restrict__ cm,
                                              float* __restrict__ sel) {
    const int lane = threadIdx.x & 63;
    const int wid  = threadIdx.x >> 6;          // b-quarter 0..3
    const int q    = blockIdx.x * 64 + lane;    // column-quad 0..32767
    const int i4   = (q >> 13) << 2;            // i*4 (uniform per block)
    const int v    = q & (VV - 1);              // vocab index
    const float4* __restrict__ w4 = reinterpret_cast<const float4*>(wv);
    const float4* __restrict__ x4 = reinterpret_cast<const float4*>(xT);
    const int xg = wid * 2;                     // x float4 group for b-quarter

    float4 acc[8];
    #pragma unroll
    for (int bb = 0; bb < 8; ++bb) acc[bb] = float4{0.f, 0.f, 0.f, 0.f};

    float4 wA[8], wB[8];
    #pragma unroll
    for (int r = 0; r < 8; ++r) wA[r] = w4[(size_t)r * WROW + q];
    float4 xc0 = x4[xg], xc1 = x4[xg + 1];

    #pragma unroll 1
    for (int k = 0; k < 128; k += 2) {
        // phase A: prefetch batch k+1 -> wB, compute batch k from wA
        #pragma unroll
        for (int r = 0; r < 8; ++r)
            wB[r] = w4[(size_t)((k + 1) * 8 + r) * WROW + q];
        #pragma unroll
        for (int r = 0; r < 8; ++r) {
            const int row = k * 8 + r;
            const int nr  = row + 1;            // <= 1016, in bounds
            float4 xn0 = x4[nr * 8 + xg];
            float4 xn1 = x4[nr * 8 + xg + 1];
            FMA_ROW(wA[r], xc0, xc1);
            xc0 = xn0; xc1 = xn1;
        }
        // phase B: prefetch batch k+2 -> wA, compute batch k+1 from wB
        if (k + 2 < 128) {
            #pragma unroll
            for (int r = 0; r < 8; ++r)
                wA[r] = w4[(size_t)((k + 2) * 8 + r) * WROW + q];
        }
        #pragma unroll
        for (int r = 0; r < 8; ++r) {
            const int row = (k + 1) * 8 + r;
            const int nr  = (row < DD - 1) ? row + 1 : DD - 1;
            float4 xn0 = x4[nr * 8 + xg];
            float4 xn1 = x4[nr * 8 + xg + 1];
            FMA_ROW(wB[r], xc0, xc1);
            xc0 = xn0; xc1 = xn1;
        }
    }

    // sigmoid epilogue (in place)
    #pragma unroll
    for (int bb = 0; bb < 8; ++bb) {
        acc[bb].x = 0.01f / (1.0f + __expf(-acc[bb].x)) + 0.001f;
        acc[bb].y = 0.01f / (1.0f + __expf(-acc[bb].y)) + 0.001f;
        acc[bb].z = 0.01f / (1.0f + __expf(-acc[bb].z)) + 0.001f;
        acc[bb].w = 0.01f / (1.0f + __expf(-acc[bb].w)) + 0.001f;
    }

    // cm[b][i][j] += sum over this wave's 64 quads (256 v's)
    #pragma unroll
    for (int bb = 0; bb < 8; ++bb) {
        float4 s = acc[bb];
        #pragma unroll
        for (int m = 1; m < 64; m <<= 1) {
            s.x += __shfl_xor(s.x, m);
            s.y += __shfl_xor(s.y, m);
            s.z += __shfl_xor(s.z, m);
            s.w += __shfl_xor(s.w, m);
        }
        if (lane < 4) {
            float val = (lane == 0) ? s.x : (lane == 1) ? s.y
                       : (lane == 2) ? s.z : s.w;
            atomicAdd(&cm[(8 * wid + bb) * 16 + i4 + lane], val);
        }
    }

    // sel[b][t][i][:] = core row where label matches
    #pragma unroll
    for (int bb = 0; bb < 8; ++bb) {
        const int b = 8 * wid + bb;
        #pragma unroll
        for (int t = 0; t < TT; ++t) {
            if (lab[b * TT + t] == v) {
                float* sp = &sel[(b * TT + t) * 16 + i4];
                sp[0] = acc[bb].x; sp[1] = acc[bb].y;
                sp[2] = acc[bb].z; sp[3] = acc[bb].w;
            }
        }
    }
}

__global__ __launch_bounds__(64) void k_final(const float* __restrict__ cm,
                                              const float* __restrict__ sel,
                                              const float* __restrict__ alpha,
                                              const float* __restrict__ beta,
                                              float* __restrict__ out) {
    __shared__ float ls[BB];
    int b = threadIdx.x;
    if (b < BB) {
        float ch[16], tmp[16];
        #pragma unroll
        for (int q = 0; q < 16; ++q) ch[q] = sel[(b * TT + 0) * 16 + q];
        for (int t = 1; t < TT; ++t) {
            const float* m = &sel[(b * TT + t) * 16];
            #pragma unroll
            for (int i2 = 0; i2 < 4; ++i2)
                #pragma unroll
                for (int j2 = 0; j2 < 4; ++j2) {
                    float s = 0.f;
                    #pragma unroll
                    for (int k = 0; k < 4; ++k) s += ch[i2*4+k] * m[k*4+j2];
                    tmp[i2*4+j2] = s;
                }
            #pragma unroll
            for (int q = 0; q < 16; ++q) ch[q] = tmp[q];
        }

        float M[16], P[16];
        #pragma unroll
        for (int q = 0; q < 16; ++q) { M[q] = cm[b*16+q]; P[q] = M[q]; }
        for (int t = 0; t < TT; ++t) {   // P = cm^(T+1)
            #pragma unroll
            for (int i2 = 0; i2 < 4; ++i2)
                #pragma unroll
                for (int j2 = 0; j2 < 4; ++j2) {
                    float s = 0.f;
                    #pragma unroll
                    for (int k = 0; k < 4; ++k) s += P[i2*4+k] * M[k*4+j2];
                    tmp[i2*4+j2] = s;
                }
            #pragma unroll
            for (int q = 0; q < 16; ++q) P[q] = tmp[q];
        }

        float a[4], be[4];
        #pragma unroll
        for (int r = 0; r < 4; ++r) { a[r] = alpha[b*4+r]; be[r] = beta[b*4+r]; }
        float un = 0.f, no = 0.f;
        #pragma unroll
        for (int i2 = 0; i2 < 4; ++i2)
            #pragma unroll
            for (int j2 = 0; j2 < 4; ++j2) {
                un += a[i2] * ch[i2*4+j2] * be[j2];
                no += a[i2] * P [i2*4+j2] * be[j2];
            }
        float prob = un / no + 0.001f;
        ls[b] = -logf(prob);
    }
    __syncthreads();
    if (threadIdx.x == 0) {
        float s = 0.f;
        for (int q = 0; q < BB; ++q) s += ls[q];
        out[0] = s / BB;
    }
}

extern "C" void kernel_launch(void* const* d_in, const int* in_sizes, int n_in,
                              void* d_out, int out_size, void* d_ws, size_t ws_size,
                              hipStream_t stream) {
    const float* in_embs = (const float*)d_in[0];
    const int*   lab     = (const int*)  d_in[1];
    const float* wa      = (const float*)d_in[2];
    const float* wb      = (const float*)d_in[3];
    const float* wv      = (const float*)d_in[4];

    float* ws    = (float*)d_ws;
    float* xT    = ws;
    float* xb    = ws + 32768;
    float* cm    = ws + 65536;
    float* sel   = ws + 66048;
    float* alpha = ws + 73216;
    float* beta  = ws + 73344;

    k_prep <<<128, 256, 0, stream>>>(in_embs, xT, xb, cm);
    k_ab   <<<64,  256, 0, stream>>>(xb, wa, wb, alpha, beta);
    k_core <<<512, 256, 0, stream>>>(wv, xT, lab, cm, sel);
    k_final<<<1,   64,  0, stream>>>(cm, sel, alpha, beta, (float*)d_out);
}

// Round 4
// 209.084 us; speedup vs baseline: 1.4695x; 1.2306x over previous
//
#include <hip/hip_runtime.h>
#include <cstdint>
#include <cstddef>

#define BB 32
#define TT 14
#define DD 1024
#define RR 4
#define VV 8192
#define NCOL (VV*RR*RR)   // 131072 columns
#define WROW (NCOL/4)     // 32768 float4 per row

typedef float f4 __attribute__((ext_vector_type(4)));

// ws layout (floats):
//  xT    : D*B   = 32768  @ 0        (xT[d*32+b])
//  xb    : B*D   = 32768  @ 32768    (b-major)
//  cm    : B*16  = 512    @ 65536
//  sel   : B*T*16= 7168   @ 66048
//  alpha : B*4   = 128    @ 73216
//  beta  : B*4   = 128    @ 73344

__global__ __launch_bounds__(256) void k_prep(const float* __restrict__ in,
                                              float* __restrict__ xT,
                                              float* __restrict__ xb,
                                              float* __restrict__ cm) {
    int tid = blockIdx.x * 256 + threadIdx.x;   // 32768 threads
    int b = tid >> 10, d = tid & 1023;
    float s = 0.f;
    #pragma unroll
    for (int t = 0; t < TT; ++t) s += in[(b * TT + t) * DD + d];
    s *= (1.0f / TT);
    xT[d * BB + b] = s;
    xb[b * DD + d] = s;
    if (tid < BB * 16) cm[tid] = 0.f;           // replaces hipMemsetAsync
}

__global__ __launch_bounds__(256) void k_ab(const float* __restrict__ xb,
                                            const float* __restrict__ wa,
                                            const float* __restrict__ wb,
                                            float* __restrict__ alpha,
                                            float* __restrict__ beta) {
    int wid  = (blockIdx.x * 256 + threadIdx.x) >> 6;
    int lane = threadIdx.x & 63;
    int b = wid >> 3, r = (wid >> 1) & 3, s = wid & 1;
    const float* wm = s ? wb : wa;
    float p = 0.f;
    #pragma unroll
    for (int k = 0; k < 16; ++k) {
        int d = lane + 64 * k;
        p += xb[b * DD + d] * wm[d * RR + r];
    }
    #pragma unroll
    for (int m = 1; m < 64; m <<= 1) p += __shfl_xor(p, m);
    if (lane == 0) {
        float v = 1.0f / (1.0f + __expf(-p)) + 0.001f;
        (s ? beta : alpha)[b * RR + r] = v;
    }
}

#define FMA_ROW(W, X0, X1)                                             \
    do {                                                               \
        acc[0].x = fmaf((W).x, (X0).x, acc[0].x);                      \
        acc[0].y = fmaf((W).y, (X0).x, acc[0].y);                      \
        acc[0].z = fmaf((W).z, (X0).x, acc[0].z);                      \
        acc[0].w = fmaf((W).w, (X0).x, acc[0].w);                      \
        acc[1].x = fmaf((W).x, (X0).y, acc[1].x);                      \
        acc[1].y = fmaf((W).y, (X0).y, acc[1].y);                      \
        acc[1].z = fmaf((W).z, (X0).y, acc[1].z);                      \
        acc[1].w = fmaf((W).w, (X0).y, acc[1].w);                      \
        acc[2].x = fmaf((W).x, (X0).z, acc[2].x);                      \
        acc[2].y = fmaf((W).y, (X0).z, acc[2].y);                      \
        acc[2].z = fmaf((W).z, (X0).z, acc[2].z);                      \
        acc[2].w = fmaf((W).w, (X0).z, acc[2].w);                      \
        acc[3].x = fmaf((W).x, (X0).w, acc[3].x);                      \
        acc[3].y = fmaf((W).y, (X0).w, acc[3].y);                      \
        acc[3].z = fmaf((W).z, (X0).w, acc[3].z);                      \
        acc[3].w = fmaf((W).w, (X0).w, acc[3].w);                      \
        acc[4].x = fmaf((W).x, (X1).x, acc[4].x);                      \
        acc[4].y = fmaf((W).y, (X1).x, acc[4].y);                      \
        acc[4].z = fmaf((W).z, (X1).x, acc[4].z);                      \
        acc[4].w = fmaf((W).w, (X1).x, acc[4].w);                      \
        acc[5].x = fmaf((W).x, (X1).y, acc[5].x);                      \
        acc[5].y = fmaf((W).y, (X1).y, acc[5].y);                      \
        acc[5].z = fmaf((W).z, (X1).y, acc[5].z);                      \
        acc[5].w = fmaf((W).w, (X1).y, acc[5].w);                      \
        acc[6].x = fmaf((W).x, (X1).z, acc[6].x);                      \
        acc[6].y = fmaf((W).y, (X1).z, acc[6].y);                      \
        acc[6].z = fmaf((W).z, (X1).z, acc[6].z);                      \
        acc[6].w = fmaf((W).w, (X1).z, acc[6].w);                      \
        acc[7].x = fmaf((W).x, (X1).w, acc[7].x);                      \
        acc[7].y = fmaf((W).y, (X1).w, acc[7].y);                      \
        acc[7].z = fmaf((W).z, (X1).w, acc[7].z);                      \
        acc[7].w = fmaf((W).w, (X1).w, acc[7].w);                      \
    } while (0)

#define LOAD_W(DST, PROW)                                                     \
    _Pragma("unroll")                                                         \
    for (int r = 0; r < 8; ++r)                                               \
        DST[r] = __builtin_nontemporal_load(                                  \
            &w4[(size_t)((PROW) * 8 + r) * WROW + q]);

#define LOAD_XO(PROW)                                                         \
    _Pragma("unroll")                                                         \
    for (int j = 0; j < 8; ++j)                                               \
        xO[j] = x4[((PROW) * 8 + (j >> 1)) * 8 + xg + (j & 1)];

#define LOAD_XE(PROW)                                                         \
    _Pragma("unroll")                                                         \
    for (int j = 0; j < 8; ++j)                                               \
        xE[j] = x4[((PROW) * 8 + 4 + (j >> 1)) * 8 + xg + (j & 1)];

// phase = 8 rows. w double-buffered one phase (512 cyc) ahead;
// x half-phase buffers xO/xE reloaded 4 rows (256 cyc) ahead of use.
#define PHASE_FULL(WCUR, WNXT, PNEXT)                                         \
    LOAD_W(WNXT, PNEXT);                                                      \
    _Pragma("unroll")                                                         \
    for (int r = 0; r < 4; ++r) FMA_ROW(WCUR[r], xO[2*r], xO[2*r+1]);         \
    LOAD_XO(PNEXT);                                                           \
    _Pragma("unroll")                                                         \
    for (int r = 0; r < 4; ++r) FMA_ROW(WCUR[4+r], xE[2*r], xE[2*r+1]);       \
    LOAD_XE(PNEXT);

#define PHASE_LAST(WCUR)                                                      \
    _Pragma("unroll")                                                         \
    for (int r = 0; r < 4; ++r) FMA_ROW(WCUR[r], xO[2*r], xO[2*r+1]);         \
    _Pragma("unroll")                                                         \
    for (int r = 0; r < 4; ++r) FMA_ROW(WCUR[4+r], xE[2*r], xE[2*r+1]);

// Each lane: 4 consecutive columns (one float4 of wv) x 8 b's, all 1024 rows.
// 4 waves of a block = the 4 b-quarters.
__global__ __launch_bounds__(256, 2) void k_core(const float* __restrict__ wv,
                                                 const float* __restrict__ xT,
                                                 const int*   __restrict__ lab,
                                                 float* __restrict__ cm,
                                                 float* __restrict__ sel) {
    const int lane = threadIdx.x & 63;
    const int wid  = threadIdx.x >> 6;          // b-quarter 0..3
    const int q    = blockIdx.x * 64 + lane;    // column-quad 0..32767
    const int i4   = (q >> 13) << 2;            // i*4 (uniform per block)
    const int v    = q & (VV - 1);              // vocab index
    const f4* __restrict__ w4 = reinterpret_cast<const f4*>(wv);
    const f4* __restrict__ x4 = reinterpret_cast<const f4*>(xT);
    const int xg = __builtin_amdgcn_readfirstlane(wid * 2);

    f4 acc[8];
    #pragma unroll
    for (int bb = 0; bb < 8; ++bb) acc[bb] = (f4){0.f, 0.f, 0.f, 0.f};

    f4 wA[8], wB[8], xO[8], xE[8];
    LOAD_W(wA, 0);
    LOAD_XO(0);
    LOAD_XE(0);

    #pragma unroll 1
    for (int p = 0; p < 126; p += 2) {
        PHASE_FULL(wA, wB, p + 1);
        PHASE_FULL(wB, wA, p + 2);
    }
    PHASE_FULL(wA, wB, 127);   // compute phase 126, prefetch 127
    PHASE_LAST(wB);            // compute phase 127

    // sigmoid epilogue (in place)
    #pragma unroll
    for (int bb = 0; bb < 8; ++bb) {
        acc[bb].x = 0.01f / (1.0f + __expf(-acc[bb].x)) + 0.001f;
        acc[bb].y = 0.01f / (1.0f + __expf(-acc[bb].y)) + 0.001f;
        acc[bb].z = 0.01f / (1.0f + __expf(-acc[bb].z)) + 0.001f;
        acc[bb].w = 0.01f / (1.0f + __expf(-acc[bb].w)) + 0.001f;
    }

    // cm[b][i][j] += sum over this wave's 64 quads (256 v's)
    #pragma unroll
    for (int bb = 0; bb < 8; ++bb) {
        f4 s = acc[bb];
        #pragma unroll
        for (int m = 1; m < 64; m <<= 1) {
            s.x += __shfl_xor(s.x, m);
            s.y += __shfl_xor(s.y, m);
            s.z += __shfl_xor(s.z, m);
            s.w += __shfl_xor(s.w, m);
        }
        if (lane < 4) {
            float val = (lane == 0) ? s.x : (lane == 1) ? s.y
                       : (lane == 2) ? s.z : s.w;
            atomicAdd(&cm[(8 * wid + bb) * 16 + i4 + lane], val);
        }
    }

    // sel[b][t][i][:] = core row where label matches
    #pragma unroll
    for (int bb = 0; bb < 8; ++bb) {
        const int b = 8 * wid + bb;
        #pragma unroll
        for (int t = 0; t < TT; ++t) {
            if (lab[b * TT + t] == v) {
                float* sp = &sel[(b * TT + t) * 16 + i4];
                sp[0] = acc[bb].x; sp[1] = acc[bb].y;
                sp[2] = acc[bb].z; sp[3] = acc[bb].w;
            }
        }
    }
}

__global__ __launch_bounds__(64) void k_final(const float* __restrict__ cm,
                                              const float* __restrict__ sel,
                                              const float* __restrict__ alpha,
                                              const float* __restrict__ beta,
                                              float* __restrict__ out) {
    __shared__ float ls[BB];
    int b = threadIdx.x;
    if (b < BB) {
        float ch[16], tmp[16];
        #pragma unroll
        for (int q = 0; q < 16; ++q) ch[q] = sel[(b * TT + 0) * 16 + q];
        for (int t = 1; t < TT; ++t) {
            const float* m = &sel[(b * TT + t) * 16];
            #pragma unroll
            for (int i2 = 0; i2 < 4; ++i2)
                #pragma unroll
                for (int j2 = 0; j2 < 4; ++j2) {
                    float s = 0.f;
                    #pragma unroll
                    for (int k = 0; k < 4; ++k) s += ch[i2*4+k] * m[k*4+j2];
                    tmp[i2*4+j2] = s;
                }
            #pragma unroll
            for (int q = 0; q < 16; ++q) ch[q] = tmp[q];
        }

        float M[16], P[16];
        #pragma unroll
        for (int q = 0; q < 16; ++q) { M[q] = cm[b*16+q]; P[q] = M[q]; }
        for (int t = 0; t < TT; ++t) {   // P = cm^(T+1)
            #pragma unroll
            for (int i2 = 0; i2 < 4; ++i2)
                #pragma unroll
                for (int j2 = 0; j2 < 4; ++j2) {
                    float s = 0.f;
                    #pragma unroll
                    for (int k = 0; k < 4; ++k) s += P[i2*4+k] * M[k*4+j2];
                    tmp[i2*4+j2] = s;
                }
            #pragma unroll
            for (int q = 0; q < 16; ++q) P[q] = tmp[q];
        }

        float a[4], be[4];
        #pragma unroll
        for (int r = 0; r < 4; ++r) { a[r] = alpha[b*4+r]; be[r] = beta[b*4+r]; }
        float un = 0.f, no = 0.f;
        #pragma unroll
        for (int i2 = 0; i2 < 4; ++i2)
            #pragma unroll
            for (int j2 = 0; j2 < 4; ++j2) {
                un += a[i2] * ch[i2*4+j2] * be[j2];
                no += a[i2] * P [i2*4+j2] * be[j2];
            }
        float prob = un / no + 0.001f;
        ls[b] = -logf(prob);
    }
    __syncthreads();
    if (threadIdx.x == 0) {
        float s = 0.f;
        for (int q = 0; q < BB; ++q) s += ls[q];
        out[0] = s / BB;
    }
}

extern "C" void kernel_launch(void* const* d_in, const int* in_sizes, int n_in,
                              void* d_out, int out_size, void* d_ws, size_t ws_size,
                              hipStream_t stream) {
    const float* in_embs = (const float*)d_in[0];
    const int*   lab     = (const int*)  d_in[1];
    const float* wa      = (const float*)d_in[2];
    const float* wb      = (const float*)d_in[3];
    const float* wv      = (const float*)d_in[4];

    float* ws    = (float*)d_ws;
    float* xT    = ws;
    float* xb    = ws + 32768;
    float* cm    = ws + 65536;
    float* sel   = ws + 66048;
    float* alpha = ws + 73216;
    float* beta  = ws + 73344;

    k_prep <<<128, 256, 0, stream>>>(in_embs, xT, xb, cm);
    k_ab   <<<64,  256, 0, stream>>>(xb, wa, wb, alpha, beta);
    k_core <<<512, 256, 0, stream>>>(wv, xT, lab, cm, sel);
    k_final<<<1,   64,  0, stream>>>(cm, sel, alpha, beta, (float*)d_out);
}

// Round 5
// 127.967 us; speedup vs baseline: 2.4010x; 1.6339x over previous
//
#include <hip/hip_runtime.h>
#include <cstdint>
#include <cstddef>

#define BB 32
#define TT 14
#define DD 1024
#define RR 4
#define VV 8192
#define NCOL (VV*RR*RR)   // 131072 columns

typedef float f32x16 __attribute__((ext_vector_type(16)));
typedef short short8 __attribute__((ext_vector_type(8)));
typedef unsigned int uint;

// ws layout (floats):
//  xb    : B*D   = 32768  @ 0       (x mean, b-major)
//  cm    : B*16  = 512    @ 32768
//  sel   : B*T*16= 7168   @ 33280
//  alpha : B*4   = 128    @ 40448
//  beta  : B*4   = 128    @ 40576
//  xfrag : 8192 uint4     @ 40704   (A-fragments, bf16-packed)

__device__ __forceinline__ ushort bf16_rne(float f) {
    uint u = __builtin_bit_cast(uint, f);
    return (ushort)((u + 0x7FFFu + ((u >> 16) & 1u)) >> 16);
}

__global__ __launch_bounds__(256) void k_prep(const float* __restrict__ in,
                                              float* __restrict__ xb,
                                              float* __restrict__ cm) {
    int tid = blockIdx.x * 256 + threadIdx.x;   // 32768 threads
    int b = tid >> 10, d = tid & 1023;
    float s = 0.f;
    #pragma unroll
    for (int t = 0; t < TT; ++t) s += in[(b * TT + t) * DD + d];
    xb[b * DD + d] = s * (1.0f / TT);
    if (tid < BB * 16) cm[tid] = 0.f;
}

// Build A-fragments: xfrag[s][l] = 8 bf16 = x[b = l&31][k = s*16 + (l>>5)*8 + j]
__global__ __launch_bounds__(64) void k_xfrag(const float* __restrict__ xb,
                                              uint4* __restrict__ xfrag) {
    int s = blockIdx.x;          // 0..63  (k-step)
    int l = threadIdx.x;         // 0..63  (lane)
    int b = l & 31;
    int kb = s * 16 + (l >> 5) * 8;
    uint u[4];
    #pragma unroll
    for (int p = 0; p < 4; ++p) {
        ushort h0 = bf16_rne(xb[b * DD + kb + 2 * p]);
        ushort h1 = bf16_rne(xb[b * DD + kb + 2 * p + 1]);
        u[p] = (uint)h0 | ((uint)h1 << 16);
    }
    xfrag[(s << 6) + l] = make_uint4(u[0], u[1], u[2], u[3]);
}

__global__ __launch_bounds__(256) void k_ab(const float* __restrict__ xb,
                                            const float* __restrict__ wa,
                                            const float* __restrict__ wb,
                                            float* __restrict__ alpha,
                                            float* __restrict__ beta) {
    int wid  = (blockIdx.x * 256 + threadIdx.x) >> 6;
    int lane = threadIdx.x & 63;
    int b = wid >> 3, r = (wid >> 1) & 3, s = wid & 1;
    const float* wm = s ? wb : wa;
    float p = 0.f;
    #pragma unroll
    for (int k = 0; k < 16; ++k) {
        int d = lane + 64 * k;
        p += xb[b * DD + d] * wm[d * RR + r];
    }
    #pragma unroll
    for (int m = 1; m < 64; m <<= 1) p += __shfl_xor(p, m);
    if (lane == 0) {
        float v = 1.0f / (1.0f + __expf(-p)) + 0.001f;
        (s ? beta : alpha)[b * RR + r] = v;
    }
}

#define LOADW(DST, STEP)                                                      \
    _Pragma("unroll")                                                         \
    for (int j = 0; j < 8; ++j)                                               \
        DST[j] = __builtin_nontemporal_load(                                  \
            wp + (size_t)((STEP) * 16 + j) * NCOL);

__device__ __forceinline__ short8 pack_bf16x8(const float* w) {
    uint u[4];
    #pragma unroll
    for (int p = 0; p < 4; ++p) {
        ushort h0 = bf16_rne(w[2 * p]);
        ushort h1 = bf16_rne(w[2 * p + 1]);
        u[p] = (uint)h0 | ((uint)h1 << 16);
    }
    return __builtin_bit_cast(short8, make_uint4(u[0], u[1], u[2], u[3]));
}

// Wave owns 32 consecutive columns x all 32 b. One 32x32x16 MFMA per k-step.
// D mapping (verified): col = lane&31, row(b) = (reg&3) + 8*(reg>>2) + 4*(lane>>5)
__global__ __launch_bounds__(256) void k_core(const float* __restrict__ wv,
                                              const uint4* __restrict__ xfrag,
                                              const int*   __restrict__ lab,
                                              float* __restrict__ cm,
                                              float* __restrict__ sel) {
    const int tid  = threadIdx.x;
    const int lane = tid & 63;
    const int wvid = tid >> 6;                     // wave 0..3
    const int n0   = blockIdx.x * 128 + wvid * 32; // wave's column base
    const int n    = n0 + (lane & 31);
    const int ii   = n >> 15;                      // r1 block (uniform/block)
    const int jj   = n & 3;                        // r2
    const int vv   = (n >> 2) & (VV - 1);          // vocab index (per lane)

    __shared__ int   lds_lab[BB * TT];
    __shared__ float cm_blk[BB][4];

    for (int idx = tid; idx < BB * TT; idx += 256) lds_lab[idx] = lab[idx];
    if (tid < BB * 4) ((float*)cm_blk)[tid] = 0.f;
    __syncthreads();

    // lane's w pointer: k-offset (lane>>5)*8, column n
    const float* wp = wv + (size_t)((lane >> 5) * 8) * NCOL + n;

    f32x16 acc;
    #pragma unroll
    for (int q = 0; q < 16; ++q) acc[q] = 0.f;

    float wrA[8], wrB[8];
    uint4 axA, axB;
    LOADW(wrA, 0);
    axA = xfrag[lane];

    #pragma unroll 1
    for (int s = 0; s < 64; s += 2) {
        LOADW(wrB, s + 1);                          // s+1 <= 63
        axB = xfrag[((s + 1) << 6) + lane];
        acc = __builtin_amdgcn_mfma_f32_32x32x16_bf16(
                  __builtin_bit_cast(short8, axA), pack_bf16x8(wrA), acc, 0, 0, 0);
        if (s + 2 < 64) {
            LOADW(wrA, s + 2);
            axA = xfrag[((s + 2) << 6) + lane];
        }
        acc = __builtin_amdgcn_mfma_f32_32x32x16_bf16(
                  __builtin_bit_cast(short8, axB), pack_bf16x8(wrB), acc, 0, 0, 0);
    }

    // epilogue: sigmoid, cm reduce, sel gather
    #pragma unroll
    for (int r = 0; r < 16; ++r) {
        float c = 0.01f / (1.0f + __expf(-acc[r])) + 0.001f;
        const int b = (r & 3) + 8 * (r >> 2) + 4 * (lane >> 5);
        // sum over the 8 vocab columns this wave holds for (b, jj)
        float sred = c;
        sred += __shfl_xor(sred, 4);
        sred += __shfl_xor(sred, 8);
        sred += __shfl_xor(sred, 16);
        if ((lane & 31) < 4) atomicAdd(&cm_blk[b][lane & 3], sred);
        // label gather
        #pragma unroll
        for (int t = 0; t < TT; ++t)
            if (lds_lab[b * TT + t] == vv)
                sel[(b * TT + t) * 16 + (ii << 2) + jj] = c;
    }
    __syncthreads();
    if (tid < BB * 4) {
        int b = tid >> 2, j = tid & 3;
        atomicAdd(&cm[b * 16 + (ii << 2) + j], ((float*)cm_blk)[tid]);
    }
}

__global__ __launch_bounds__(64) void k_final(const float* __restrict__ cm,
                                              const float* __restrict__ sel,
                                              const float* __restrict__ alpha,
                                              const float* __restrict__ beta,
                                              float* __restrict__ out) {
    __shared__ float ls[BB];
    int b = threadIdx.x;
    if (b < BB) {
        float ch[16], tmp[16];
        #pragma unroll
        for (int q = 0; q < 16; ++q) ch[q] = sel[(b * TT + 0) * 16 + q];
        for (int t = 1; t < TT; ++t) {
            const float* m = &sel[(b * TT + t) * 16];
            #pragma unroll
            for (int i2 = 0; i2 < 4; ++i2)
                #pragma unroll
                for (int j2 = 0; j2 < 4; ++j2) {
                    float s = 0.f;
                    #pragma unroll
                    for (int k = 0; k < 4; ++k) s += ch[i2*4+k] * m[k*4+j2];
                    tmp[i2*4+j2] = s;
                }
            #pragma unroll
            for (int q = 0; q < 16; ++q) ch[q] = tmp[q];
        }

        float M[16], P[16];
        #pragma unroll
        for (int q = 0; q < 16; ++q) { M[q] = cm[b*16+q]; P[q] = M[q]; }
        for (int t = 0; t < TT; ++t) {   // P = cm^(T+1)
            #pragma unroll
            for (int i2 = 0; i2 < 4; ++i2)
                #pragma unroll
                for (int j2 = 0; j2 < 4; ++j2) {
                    float s = 0.f;
                    #pragma unroll
                    for (int k = 0; k < 4; ++k) s += P[i2*4+k] * M[k*4+j2];
                    tmp[i2*4+j2] = s;
                }
            #pragma unroll
            for (int q = 0; q < 16; ++q) P[q] = tmp[q];
        }

        float a[4], be[4];
        #pragma unroll
        for (int r = 0; r < 4; ++r) { a[r] = alpha[b*4+r]; be[r] = beta[b*4+r]; }
        float un = 0.f, no = 0.f;
        #pragma unroll
        for (int i2 = 0; i2 < 4; ++i2)
            #pragma unroll
            for (int j2 = 0; j2 < 4; ++j2) {
                un += a[i2] * ch[i2*4+j2] * be[j2];
                no += a[i2] * P [i2*4+j2] * be[j2];
            }
        float prob = un / no + 0.001f;
        ls[b] = -logf(prob);
    }
    __syncthreads();
    if (threadIdx.x == 0) {
        float s = 0.f;
        for (int q = 0; q < BB; ++q) s += ls[q];
        out[0] = s / BB;
    }
}

extern "C" void kernel_launch(void* const* d_in, const int* in_sizes, int n_in,
                              void* d_out, int out_size, void* d_ws, size_t ws_size,
                              hipStream_t stream) {
    const float* in_embs = (const float*)d_in[0];
    const int*   lab     = (const int*)  d_in[1];
    const float* wa      = (const float*)d_in[2];
    const float* wb      = (const float*)d_in[3];
    const float* wv      = (const float*)d_in[4];

    float* ws    = (float*)d_ws;
    float* xb    = ws;
    float* cm    = ws + 32768;
    float* sel   = ws + 33280;
    float* alpha = ws + 40448;
    float* beta  = ws + 40576;
    uint4* xfrag = (uint4*)(ws + 40704);

    k_prep <<<128,  256, 0, stream>>>(in_embs, xb, cm);
    k_xfrag<<<64,   64,  0, stream>>>(xb, xfrag);
    k_ab   <<<64,   256, 0, stream>>>(xb, wa, wb, alpha, beta);
    k_core <<<1024, 256, 0, stream>>>(wv, xfrag, lab, cm, sel);
    k_final<<<1,    64,  0, stream>>>(cm, sel, alpha, beta, (float*)d_out);
}

// Round 6
// 115.811 us; speedup vs baseline: 2.6531x; 1.1050x over previous
//
#include <hip/hip_runtime.h>
#include <cstdint>
#include <cstddef>

#define BB 32
#define TT 14
#define DD 1024
#define RR 4
#define VV 8192
#define NCOL (VV*RR*RR)   // 131072 columns

typedef float f32x16 __attribute__((ext_vector_type(16)));
typedef float f4 __attribute__((ext_vector_type(4)));
typedef short short8 __attribute__((ext_vector_type(8)));
typedef unsigned int uint;

// ws layout (floats):
//  cm    : B*16   = 512   @ 0
//  sel   : B*T*16 = 7168  @ 512
//  alpha : B*4    = 128   @ 7680
//  beta  : B*4    = 128   @ 7808
//  xfrag : 8192 uint4     @ 7936   (A-fragments, bf16, 32 KB)

// pack hi16(a) | hi16(b)<<16  (bf16 truncation via byte-perm)
__device__ __forceinline__ uint pack2(float a, float b) {
    return __builtin_amdgcn_perm(__builtin_bit_cast(uint, b),
                                 __builtin_bit_cast(uint, a), 0x07060302u);
}

__device__ __forceinline__ short8 packw(const float* w) {
    uint4 u = make_uint4(pack2(w[0], w[1]), pack2(w[2], w[3]),
                         pack2(w[4], w[5]), pack2(w[6], w[7]));
    return __builtin_bit_cast(short8, u);
}

// One block per b: mean over T -> LDS; emit xfrag slice; alpha/beta dots; zero cm.
__global__ __launch_bounds__(256) void k_prep_all(const float* __restrict__ in,
                                                  const float* __restrict__ wa,
                                                  const float* __restrict__ wb,
                                                  ushort* __restrict__ xfrag_us,
                                                  float* __restrict__ alpha,
                                                  float* __restrict__ beta,
                                                  float* __restrict__ cm) {
    __shared__ float xl[DD];
    const int b   = blockIdx.x;
    const int tid = threadIdx.x;
    const int d0  = tid * 4;

    f4 s4 = (f4){0.f, 0.f, 0.f, 0.f};
    #pragma unroll
    for (int t = 0; t < TT; ++t) {
        f4 v = *reinterpret_cast<const f4*>(&in[((b * TT + t) << 10) + d0]);
        s4 += v;
    }
    s4 *= (1.0f / TT);
    *reinterpret_cast<f4*>(&xl[d0]) = s4;

    if (b == 0) { cm[tid] = 0.f; cm[tid + 256] = 0.f; }

    // xfrag: lane l = b + 32*h holds k = s*16 + h*8 + j  (j=0..7) of step s
    {
        const int s  = d0 >> 4;
        const int h  = (d0 >> 3) & 1;
        const int j0 = d0 & 7;           // 0 or 4
        uint2 u;
        u.x = pack2(s4.x, s4.y);
        u.y = pack2(s4.z, s4.w);
        *reinterpret_cast<uint2*>(&xfrag_us[((s * 64 + b + 32 * h) << 3) + j0]) = u;
    }

    __syncthreads();

    // alpha/beta: 8 dot products over xl
    const int wave = tid >> 6, lane = tid & 63;
    for (int p = wave; p < 8; p += 4) {
        const int r = p >> 1, sf = p & 1;
        const float* wm = sf ? wb : wa;
        float acc = 0.f;
        #pragma unroll
        for (int k = 0; k < 16; ++k) {
            int d = lane + 64 * k;
            acc += xl[d] * wm[d * RR + r];
        }
        #pragma unroll
        for (int m = 1; m < 64; m <<= 1) acc += __shfl_xor(acc, m);
        if (lane == 0) {
            float v = 1.0f / (1.0f + __expf(-acc)) + 0.001f;
            (sf ? beta : alpha)[b * RR + r] = v;
        }
    }
}

#define LOADW(DST, STEP)                                                      \
    _Pragma("unroll")                                                         \
    for (int j = 0; j < 8; ++j)                                               \
        DST[j] = __builtin_nontemporal_load(                                  \
            wp + (size_t)((STEP) * 16 + j) * NCOL);

// Wave owns 32 consecutive columns x all 32 b. One 32x32x16 MFMA per k-step.
// D mapping: col = lane&31, row(b) = (reg&3) + 8*(reg>>2) + 4*(lane>>5)
__global__ __launch_bounds__(256) void k_core(const float* __restrict__ wv,
                                              const uint4* __restrict__ xfrag,
                                              const int*   __restrict__ lab,
                                              float* __restrict__ cm,
                                              float* __restrict__ sel) {
    const int tid  = threadIdx.x;
    const int lane = tid & 63;
    const int wvid = tid >> 6;                     // wave 0..3
    const int n0   = blockIdx.x * 128 + wvid * 32; // wave's column base
    const int n    = n0 + (lane & 31);
    const int ii   = n >> 15;                      // r1 block (uniform/block)
    const int jj   = n & 3;                        // r2
    const int vv   = (n >> 2) & (VV - 1);          // vocab index (per lane)

    __shared__ int   lds_lab[BB * TT];
    __shared__ float cm_blk[BB][4];

    for (int idx = tid; idx < BB * TT; idx += 256) lds_lab[idx] = lab[idx];
    if (tid < BB * 4) ((float*)cm_blk)[tid] = 0.f;
    __syncthreads();

    const float* wp = wv + (size_t)((lane >> 5) * 8) * NCOL + n;

    f32x16 acc;
    #pragma unroll
    for (int q = 0; q < 16; ++q) acc[q] = 0.f;

    float w0[8], w1[8], w2[8], w3[8];
    uint4 ax0, ax1, ax2, ax3;
    LOADW(w0, 0); ax0 = xfrag[lane];
    LOADW(w1, 1); ax1 = xfrag[64 + lane];

    #pragma unroll 1
    for (int s = 0; s < 64; s += 4) {
        LOADW(w2, s + 2); ax2 = xfrag[((s + 2) << 6) + lane];
        LOADW(w3, s + 3); ax3 = xfrag[((s + 3) << 6) + lane];
        acc = __builtin_amdgcn_mfma_f32_32x32x16_bf16(
                  __builtin_bit_cast(short8, ax0), packw(w0), acc, 0, 0, 0);
        acc = __builtin_amdgcn_mfma_f32_32x32x16_bf16(
                  __builtin_bit_cast(short8, ax1), packw(w1), acc, 0, 0, 0);
        if (s + 4 < 64) {
            LOADW(w0, s + 4); ax0 = xfrag[((s + 4) << 6) + lane];
            LOADW(w1, s + 5); ax1 = xfrag[((s + 5) << 6) + lane];
        }
        acc = __builtin_amdgcn_mfma_f32_32x32x16_bf16(
                  __builtin_bit_cast(short8, ax2), packw(w2), acc, 0, 0, 0);
        acc = __builtin_amdgcn_mfma_f32_32x32x16_bf16(
                  __builtin_bit_cast(short8, ax3), packw(w3), acc, 0, 0, 0);
    }

    // epilogue: sigmoid, cm reduce, sel gather
    #pragma unroll
    for (int r = 0; r < 16; ++r) {
        float c = 0.01f / (1.0f + __expf(-acc[r])) + 0.001f;
        const int b = (r & 3) + 8 * (r >> 2) + 4 * (lane >> 5);
        float sred = c;
        sred += __shfl_xor(sred, 4);
        sred += __shfl_xor(sred, 8);
        sred += __shfl_xor(sred, 16);
        if ((lane & 31) < 4) atomicAdd(&cm_blk[b][lane & 3], sred);
        #pragma unroll
        for (int t = 0; t < TT; ++t)
            if (lds_lab[b * TT + t] == vv)
                sel[(b * TT + t) * 16 + (ii << 2) + jj] = c;
    }
    __syncthreads();
    if (tid < BB * 4) {
        int b = tid >> 2, j = tid & 3;
        atomicAdd(&cm[b * 16 + (ii << 2) + j], ((float*)cm_blk)[tid]);
    }
}

__global__ __launch_bounds__(64) void k_final(const float* __restrict__ cm,
                                              const float* __restrict__ sel,
                                              const float* __restrict__ alpha,
                                              const float* __restrict__ beta,
                                              float* __restrict__ out) {
    __shared__ float ls[BB];
    int b = threadIdx.x;
    if (b < BB) {
        float ch[16], tmp[16];
        #pragma unroll
        for (int q = 0; q < 16; ++q) ch[q] = sel[(b * TT + 0) * 16 + q];
        for (int t = 1; t < TT; ++t) {
            const float* m = &sel[(b * TT + t) * 16];
            #pragma unroll
            for (int i2 = 0; i2 < 4; ++i2)
                #pragma unroll
                for (int j2 = 0; j2 < 4; ++j2) {
                    float s = 0.f;
                    #pragma unroll
                    for (int k = 0; k < 4; ++k) s += ch[i2*4+k] * m[k*4+j2];
                    tmp[i2*4+j2] = s;
                }
            #pragma unroll
            for (int q = 0; q < 16; ++q) ch[q] = tmp[q];
        }

        float M[16], P[16];
        #pragma unroll
        for (int q = 0; q < 16; ++q) { M[q] = cm[b*16+q]; P[q] = M[q]; }
        for (int t = 0; t < TT; ++t) {   // P = cm^(T+1)
            #pragma unroll
            for (int i2 = 0; i2 < 4; ++i2)
                #pragma unroll
                for (int j2 = 0; j2 < 4; ++j2) {
                    float s = 0.f;
                    #pragma unroll
                    for (int k = 0; k < 4; ++k) s += P[i2*4+k] * M[k*4+j2];
                    tmp[i2*4+j2] = s;
                }
            #pragma unroll
            for (int q = 0; q < 16; ++q) P[q] = tmp[q];
        }

        float a[4], be[4];
        #pragma unroll
        for (int r = 0; r < 4; ++r) { a[r] = alpha[b*4+r]; be[r] = beta[b*4+r]; }
        float un = 0.f, no = 0.f;
        #pragma unroll
        for (int i2 = 0; i2 < 4; ++i2)
            #pragma unroll
            for (int j2 = 0; j2 < 4; ++j2) {
                un += a[i2] * ch[i2*4+j2] * be[j2];
                no += a[i2] * P [i2*4+j2] * be[j2];
            }
        float prob = un / no + 0.001f;
        ls[b] = -logf(prob);
    }
    __syncthreads();
    if (threadIdx.x == 0) {
        float s = 0.f;
        for (int q = 0; q < BB; ++q) s += ls[q];
        out[0] = s / BB;
    }
}

extern "C" void kernel_launch(void* const* d_in, const int* in_sizes, int n_in,
                              void* d_out, int out_size, void* d_ws, size_t ws_size,
                              hipStream_t stream) {
    const float* in_embs = (const float*)d_in[0];
    const int*   lab     = (const int*)  d_in[1];
    const float* wa      = (const float*)d_in[2];
    const float* wb      = (const float*)d_in[3];
    const float* wv      = (const float*)d_in[4];

    float* ws    = (float*)d_ws;
    float* cm    = ws;
    float* sel   = ws + 512;
    float* alpha = ws + 7680;
    float* beta  = ws + 7808;
    uint4* xfrag = (uint4*)(ws + 7936);

    k_prep_all<<<32,   256, 0, stream>>>(in_embs, wa, wb, (ushort*)xfrag,
                                         alpha, beta, cm);
    k_core    <<<1024, 256, 0, stream>>>(wv, xfrag, lab, cm, sel);
    k_final   <<<1,    64,  0, stream>>>(cm, sel, alpha, beta, (float*)d_out);
}